// Round 6
// baseline (369.190 us; speedup 1.0000x reference)
//
#include <hip/hip_runtime.h>
#include <hip/hip_bf16.h>

#define DFEAT 256

typedef __attribute__((ext_vector_type(8))) short bf16x8;
typedef __attribute__((ext_vector_type(4))) float f32x4;

__device__ __forceinline__ float bf2f(unsigned short u) {
  return __builtin_bit_cast(float, ((unsigned)u) << 16);
}
__device__ __forceinline__ unsigned short f2bf(float f) {
  __hip_bfloat16 h = __float2bfloat16(f);  // RTNE
  return *reinterpret_cast<unsigned short*>(&h);
}
__device__ __forceinline__ void gload_lds16(const void* g, void* l) {
  __builtin_amdgcn_global_load_lds(
      (const __attribute__((address_space(1))) void*)g,
      (__attribute__((address_space(3))) void*)l, 16, 0, 0);
}

// ---------------- CSR construction ----------------

__global__ void k_count(const int* __restrict__ ei0, int E, int* __restrict__ cnt) {
  int i = blockIdx.x * blockDim.x + threadIdx.x;
  if (i < E) atomicAdd(&cnt[ei0[i]], 1);
}

__global__ __launch_bounds__(256) void k_scan1(const int* __restrict__ cnt, int N,
                                               int* __restrict__ incl,
                                               int* __restrict__ bsum,
                                               float* __restrict__ dis) {
  __shared__ int sh[256];
  int t = threadIdx.x;
  int i = blockIdx.x * 256 + t;
  int v = (i < N) ? cnt[i] : 0;
  sh[t] = v;
  __syncthreads();
  for (int o = 1; o < 256; o <<= 1) {
    int u = (t >= o) ? sh[t - o] : 0;
    __syncthreads();
    sh[t] += u;
    __syncthreads();
  }
  if (i < N) {
    incl[i] = sh[t];
    dis[i] = rsqrtf((float)(v + 1));
  }
  if (t == 255) bsum[blockIdx.x] = sh[255];
}

__global__ __launch_bounds__(256) void k_scan2(const int* __restrict__ bsum, int nb,
                                               int* __restrict__ boff) {
  __shared__ int sh[256];
  int t = threadIdx.x;
  int v = (t < nb) ? bsum[t] : 0;
  sh[t] = v;
  __syncthreads();
  for (int o = 1; o < 256; o <<= 1) {
    int u = (t >= o) ? sh[t - o] : 0;
    __syncthreads();
    sh[t] += u;
    __syncthreads();
  }
  if (t < nb) boff[t] = sh[t] - v;  // exclusive
}

__global__ __launch_bounds__(256) void k_scan3(const int* __restrict__ cnt,
                                               const int* __restrict__ incl,
                                               const int* __restrict__ boff, int N, int E,
                                               int* __restrict__ rowptr) {
  int i = blockIdx.x * 256 + threadIdx.x;
  if (i < N) rowptr[i] = boff[blockIdx.x] + incl[i] - cnt[i];
  if (i == 0) rowptr[N] = E;
}

__global__ void k_scatter(const int* __restrict__ ei0, const int* __restrict__ ei1, int E,
                          const int* __restrict__ rowptr, int* __restrict__ cursor,
                          int* __restrict__ cols) {
  int i = blockIdx.x * blockDim.x + threadIdx.x;
  if (i >= E) return;
  int r = ei0[i];
  int pos = rowptr[r] + atomicAdd(&cursor[r], 1);
  cols[pos] = ei1[i];
}

// ---------------- converts ----------------

__global__ void k_f2bf(const float* __restrict__ src, unsigned short* __restrict__ dst,
                       int n4) {
  int i = blockIdx.x * blockDim.x + threadIdx.x;
  if (i >= n4) return;
  float4 f = *(const float4*)(src + (size_t)i * 4);
  ushort4 u;
  u.x = f2bf(f.x); u.y = f2bf(f.y); u.z = f2bf(f.z); u.w = f2bf(f.w);
  *(ushort4*)(dst + (size_t)i * 4) = u;
}

// Combined weights for the pure-L chain:
//   out = x(W0-W2) + S1(W1-3W3) + S2(2W2) + S3(4W3) + b,  S_k = L^k x
// W[4][256][256] (g,k,n) f32 -> WT[4][256][256] (g,n,k) bf16 with combos.
__global__ __launch_bounds__(256) void k_wt(const float* __restrict__ W,
                                            unsigned short* __restrict__ WT) {
  int idx = blockIdx.x * 256 + threadIdx.x;  // (k,n) over 65536
  int n = idx & 255;
  int k = idx >> 8;
  float w0 = W[idx];
  float w1 = W[65536 + idx];
  float w2 = W[2 * 65536 + idx];
  float w3 = W[3 * 65536 + idx];
  int t = (n << 8) | k;  // transposed (n,k)
  WT[t]               = f2bf(w0 - w2);
  WT[65536 + t]       = f2bf(w1 - 3.0f * w3);
  WT[2 * 65536 + t]   = f2bf(2.0f * w2);
  WT[3 * 65536 + t]   = f2bf(4.0f * w3);
}

// ---------------- SpMM (bf16): y = L v  (pure Laplacian apply) ----------------
// One wave per row; lane owns 4 contiguous feats (8 B). Wave gathers 512 B per
// edge, fully coalesced. No LDS, no shfl, no barrier. Unroll x2 -> two
// independent gather chains. 4 rows per 256-thread block.

__global__ __launch_bounds__(256) void k_spmm_bf(
    const unsigned short* __restrict__ v, unsigned short* __restrict__ y,
    const int* __restrict__ rowptr, const int* __restrict__ cols,
    const float* __restrict__ dis, int N) {
  int r = blockIdx.x * 4 + (threadIdx.x >> 6);
  if (r >= N) return;
  int lane = threadIdx.x & 63;
  int fo = lane * 4;
  int e0 = rowptr[r], e1 = rowptr[r + 1];
  float dr = dis[r];
  float a0 = 0.f, a1 = 0.f, a2 = 0.f, a3 = 0.f;

  int e = e0;
  for (; e + 1 < e1; e += 2) {
    int cA = cols[e], cB = cols[e + 1];
    float lA = -dr * dis[cA] + (cA == r ? 1.f : 0.f);
    float lB = -dr * dis[cB] + (cB == r ? 1.f : 0.f);
    uint2 uA = *(const uint2*)(v + (size_t)cA * DFEAT + fo);
    uint2 uB = *(const uint2*)(v + (size_t)cB * DFEAT + fo);
    a0 += lA * bf2f(uA.x & 0xffff) + lB * bf2f(uB.x & 0xffff);
    a1 += lA * bf2f(uA.x >> 16)    + lB * bf2f(uB.x >> 16);
    a2 += lA * bf2f(uA.y & 0xffff) + lB * bf2f(uB.y & 0xffff);
    a3 += lA * bf2f(uA.y >> 16)    + lB * bf2f(uB.y >> 16);
  }
  if (e < e1) {
    int c = cols[e];
    float lv = -dr * dis[c] + (c == r ? 1.f : 0.f);
    uint2 u = *(const uint2*)(v + (size_t)c * DFEAT + fo);
    a0 += lv * bf2f(u.x & 0xffff);
    a1 += lv * bf2f(u.x >> 16);
    a2 += lv * bf2f(u.y & 0xffff);
    a3 += lv * bf2f(u.y >> 16);
  }

  // appended self-loop: (1 - dr^2) * v[r]
  float sc = 1.0f - dr * dr;
  uint2 uv = *(const uint2*)(v + (size_t)r * DFEAT + fo);
  a0 += sc * bf2f(uv.x & 0xffff);
  a1 += sc * bf2f(uv.x >> 16);
  a2 += sc * bf2f(uv.y & 0xffff);
  a3 += sc * bf2f(uv.y >> 16);

  uint2 o;
  o.x = (unsigned)f2bf(a0) | ((unsigned)f2bf(a1) << 16);
  o.y = (unsigned)f2bf(a2) | ((unsigned)f2bf(a3) << 16);
  *(uint2*)(y + (size_t)r * DFEAT + fo) = o;
}

// ---------------- fused MFMA GEMM: out = sum_g Ag @ Wg' + bias ----------------
// 128x128 tile, 4 waves, double-buffered LDS, 2-phase overlap.

__global__ __launch_bounds__(256) void k_gemm4(
    const unsigned short* __restrict__ A0, const unsigned short* __restrict__ A1,
    const unsigned short* __restrict__ A2, const unsigned short* __restrict__ A3,
    const unsigned short* __restrict__ WT,  // [4][256][256] (g,n,k) combined
    const float* __restrict__ bias, float* __restrict__ C, int N) {
  __shared__ __align__(16) unsigned short As[2][128 * 64];
  __shared__ __align__(16) unsigned short Bs[2][128 * 64];
  int tid = threadIdx.x;
  int lane = tid & 63;
  int w = tid >> 6;
  int wm = w >> 1, wn = w & 1;
  int brow = blockIdx.x * 128;
  int bcol = blockIdx.y * 128;

  f32x4 acc[4][4] = {};

  int srow = w * 32 + (lane >> 3);
  int skb = ((lane & 7) ^ (lane >> 3)) << 4;

  auto stage = [&](int buf, int it) {
    int g = it >> 2;
    int k0 = (it & 3) * 64;
    const unsigned short* Asrc = g == 0 ? A0 : g == 1 ? A1 : g == 2 ? A2 : A3;
    const unsigned short* Bsrc = WT + (g << 16);
#pragma unroll
    for (int c = 0; c < 4; ++c) {
      int r = srow + c * 8;
      int grow = brow + r;
      if (grow >= N) grow = N - 1;
      gload_lds16(Asrc + (size_t)grow * DFEAT + k0 + (skb >> 1),
                  (char*)As[buf] + (w * 32 + c * 8) * 128);
      gload_lds16(Bsrc + (size_t)(bcol + r) * DFEAT + k0 + (skb >> 1),
                  (char*)Bs[buf] + (w * 32 + c * 8) * 128);
    }
  };

  stage(0, 0);
  __syncthreads();  // vmcnt(0) + barrier: tile 0 ready

  for (int it = 0; it < 16; ++it) {
    int cur = it & 1;
    if (it < 15) stage(cur ^ 1, it + 1);  // issue next tile, stays in flight
#pragma unroll
    for (int ks = 0; ks < 2; ++ks) {
      bf16x8 af[4], bfr[4];
#pragma unroll
      for (int i = 0; i < 4; ++i) {
        int row = wm * 64 + i * 16 + (lane & 15);
        int kb = (ks * 64 + ((lane >> 4) << 4)) ^ ((row & 7) << 4);
        af[i] = *(const bf16x8*)((const char*)As[cur] + row * 128 + kb);
      }
#pragma unroll
      for (int j = 0; j < 4; ++j) {
        int row = wn * 64 + j * 16 + (lane & 15);
        int kb = (ks * 64 + ((lane >> 4) << 4)) ^ ((row & 7) << 4);
        bfr[j] = *(const bf16x8*)((const char*)Bs[cur] + row * 128 + kb);
      }
#pragma unroll
      for (int i = 0; i < 4; ++i)
#pragma unroll
        for (int j = 0; j < 4; ++j)
          acc[i][j] = __builtin_amdgcn_mfma_f32_16x16x32_bf16(af[i], bfr[j], acc[i][j], 0, 0, 0);
    }
    if (it < 15) __syncthreads();  // drain next-tile loads + guard buffer reuse
  }

#pragma unroll
  for (int i = 0; i < 4; ++i) {
    int rowb = brow + wm * 64 + i * 16 + (lane >> 4) * 4;
#pragma unroll
    for (int j = 0; j < 4; ++j) {
      int col = bcol + wn * 64 + j * 16 + (lane & 15);
      float b = bias[col];
#pragma unroll
      for (int q = 0; q < 4; ++q) {
        int r = rowb + q;
        if (r < N) C[(size_t)r * DFEAT + col] = acc[i][j][q] + b;
      }
    }
  }
}

// ---------------- launch ----------------

extern "C" void kernel_launch(void* const* d_in, const int* in_sizes, int n_in,
                              void* d_out, int out_size, void* d_ws, size_t ws_size,
                              hipStream_t stream) {
  const float* x = (const float*)d_in[0];
  const int* ei = (const int*)d_in[1];
  const float* weight = (const float*)d_in[2];
  const float* bias = (const float*)d_in[3];
  float* out = (float*)d_out;

  int N = in_sizes[0] / DFEAT;
  int E = in_sizes[1] / 2;
  const int* ei0 = ei;
  const int* ei1 = ei + E;

  char* ws = (char*)d_ws;
  size_t off = 0;
  auto alloc = [&](size_t bytes) {
    void* p = ws + off;
    off = (off + bytes + 255) & ~(size_t)255;
    return p;
  };
  int* cnt = (int*)alloc((size_t)2 * N * sizeof(int));
  int* cursor = cnt + N;
  int* rowptr = (int*)alloc((size_t)(N + 1) * sizeof(int));
  float* dis = (float*)alloc((size_t)N * sizeof(float));
  int* cols = (int*)alloc((size_t)E * sizeof(int));
  int* incl = (int*)alloc((size_t)N * sizeof(int));
  int* bsum = (int*)alloc(256 * sizeof(int));
  int* boff = (int*)alloc(256 * sizeof(int));
  unsigned short* xbf = (unsigned short*)alloc((size_t)N * DFEAT * 2);
  unsigned short* S1 = (unsigned short*)alloc((size_t)N * DFEAT * 2);
  unsigned short* S2 = (unsigned short*)alloc((size_t)N * DFEAT * 2);
  unsigned short* S3 = (unsigned short*)alloc((size_t)N * DFEAT * 2);
  unsigned short* WT = (unsigned short*)alloc((size_t)4 * DFEAT * DFEAT * 2);

  hipMemsetAsync(cnt, 0, (size_t)2 * N * sizeof(int), stream);

  int eb = (E + 255) / 256;
  int nb = (N + 255) / 256;
  k_count<<<eb, 256, 0, stream>>>(ei0, E, cnt);
  k_scan1<<<nb, 256, 0, stream>>>(cnt, N, incl, bsum, dis);
  k_scan2<<<1, 256, 0, stream>>>(bsum, nb, boff);
  k_scan3<<<nb, 256, 0, stream>>>(cnt, incl, boff, N, E, rowptr);
  k_scatter<<<eb, 256, 0, stream>>>(ei0, ei1, E, rowptr, cursor, cols);

  int n4 = N * DFEAT / 4;
  k_f2bf<<<(n4 + 255) / 256, 256, 0, stream>>>(x, xbf, n4);
  k_wt<<<DFEAT * DFEAT / 256, 256, 0, stream>>>(weight, WT);

  // Pure chain: S1 = L x ; S2 = L S1 ; S3 = L S2
  int sgrid = (N + 3) / 4;
  k_spmm_bf<<<sgrid, 256, 0, stream>>>(xbf, S1, rowptr, cols, dis, N);
  k_spmm_bf<<<sgrid, 256, 0, stream>>>(S1, S2, rowptr, cols, dis, N);
  k_spmm_bf<<<sgrid, 256, 0, stream>>>(S2, S3, rowptr, cols, dis, N);

  dim3 ggrid((N + 127) / 128, DFEAT / 128);
  k_gemm4<<<ggrid, 256, 0, stream>>>(xbf, S1, S2, S3, WT, bias, out, N);
}

// Round 7
// 348.825 us; speedup vs baseline: 1.0584x; 1.0584x over previous
//
#include <hip/hip_runtime.h>
#include <hip/hip_bf16.h>

#define DFEAT 256

typedef __attribute__((ext_vector_type(8))) short bf16x8;
typedef __attribute__((ext_vector_type(4))) float f32x4;

__device__ __forceinline__ float bf2f(unsigned short u) {
  return __builtin_bit_cast(float, ((unsigned)u) << 16);
}
__device__ __forceinline__ unsigned short f2bf(float f) {
  __hip_bfloat16 h = __float2bfloat16(f);  // RTNE
  return *reinterpret_cast<unsigned short*>(&h);
}
__device__ __forceinline__ void gload_lds16(const void* g, void* l) {
  __builtin_amdgcn_global_load_lds(
      (const __attribute__((address_space(1))) void*)g,
      (__attribute__((address_space(3))) void*)l, 16, 0, 0);
}

// ---------------- CSR construction ----------------

__global__ void k_count(const int* __restrict__ ei0, int E, int* __restrict__ cnt) {
  int i = blockIdx.x * blockDim.x + threadIdx.x;
  if (i < E) atomicAdd(&cnt[ei0[i]], 1);
}

__global__ __launch_bounds__(256) void k_scan1(const int* __restrict__ cnt, int N,
                                               int* __restrict__ incl,
                                               int* __restrict__ bsum,
                                               float* __restrict__ dis) {
  __shared__ int sh[256];
  int t = threadIdx.x;
  int i = blockIdx.x * 256 + t;
  int v = (i < N) ? cnt[i] : 0;
  sh[t] = v;
  __syncthreads();
  for (int o = 1; o < 256; o <<= 1) {
    int u = (t >= o) ? sh[t - o] : 0;
    __syncthreads();
    sh[t] += u;
    __syncthreads();
  }
  if (i < N) {
    incl[i] = sh[t];
    dis[i] = rsqrtf((float)(v + 1));
  }
  if (t == 255) bsum[blockIdx.x] = sh[255];
}

__global__ __launch_bounds__(256) void k_scan2(const int* __restrict__ bsum, int nb,
                                               int* __restrict__ boff) {
  __shared__ int sh[256];
  int t = threadIdx.x;
  int v = (t < nb) ? bsum[t] : 0;
  sh[t] = v;
  __syncthreads();
  for (int o = 1; o < 256; o <<= 1) {
    int u = (t >= o) ? sh[t - o] : 0;
    __syncthreads();
    sh[t] += u;
    __syncthreads();
  }
  if (t < nb) boff[t] = sh[t] - v;  // exclusive
}

__global__ __launch_bounds__(256) void k_scan3(const int* __restrict__ cnt,
                                               const int* __restrict__ incl,
                                               const int* __restrict__ boff, int N, int E,
                                               int* __restrict__ rowptr) {
  int i = blockIdx.x * 256 + threadIdx.x;
  if (i < N) rowptr[i] = boff[blockIdx.x] + incl[i] - cnt[i];
  if (i == 0) rowptr[N] = E;
}

__global__ void k_scatter(const int* __restrict__ ei0, const int* __restrict__ ei1, int E,
                          const int* __restrict__ rowptr, int* __restrict__ cursor,
                          int* __restrict__ cols) {
  int i = blockIdx.x * blockDim.x + threadIdx.x;
  if (i >= E) return;
  int r = ei0[i];
  int pos = rowptr[r] + atomicAdd(&cursor[r], 1);
  cols[pos] = ei1[i];
}

// ---------------- converts ----------------

__global__ void k_f2bf(const float* __restrict__ src, unsigned short* __restrict__ dst,
                       int n4) {
  int i = blockIdx.x * blockDim.x + threadIdx.x;
  if (i >= n4) return;
  float4 f = *(const float4*)(src + (size_t)i * 4);
  ushort4 u;
  u.x = f2bf(f.x); u.y = f2bf(f.y); u.z = f2bf(f.z); u.w = f2bf(f.w);
  *(ushort4*)(dst + (size_t)i * 4) = u;
}

// Combined weights for the pure-L chain:
//   out = x(W0-W2) + S1(W1-3W3) + S2(2W2) + S3(4W3) + b,  S_k = L^k x
__global__ __launch_bounds__(256) void k_wt(const float* __restrict__ W,
                                            unsigned short* __restrict__ WT) {
  int idx = blockIdx.x * 256 + threadIdx.x;  // (k,n) over 65536
  int n = idx & 255;
  int k = idx >> 8;
  float w0 = W[idx];
  float w1 = W[65536 + idx];
  float w2 = W[2 * 65536 + idx];
  float w3 = W[3 * 65536 + idx];
  int t = (n << 8) | k;  // transposed (n,k)
  WT[t]               = f2bf(w0 - w2);
  WT[65536 + t]       = f2bf(w1 - 3.0f * w3);
  WT[2 * 65536 + t]   = f2bf(2.0f * w2);
  WT[3 * 65536 + t]   = f2bf(4.0f * w3);
}

// ---------------- SpMM (bf16): y = L v  (pure Laplacian apply) ----------------
// One wave per row; lane owns 4 contiguous feats. At memory-system ceiling
// (~one compulsory L2 miss per operand line per XCD; L3-service bound).

__global__ __launch_bounds__(256) void k_spmm_bf(
    const unsigned short* __restrict__ v, unsigned short* __restrict__ y,
    const int* __restrict__ rowptr, const int* __restrict__ cols,
    const float* __restrict__ dis, int N) {
  int r = blockIdx.x * 4 + (threadIdx.x >> 6);
  if (r >= N) return;
  int lane = threadIdx.x & 63;
  int fo = lane * 4;
  int e0 = rowptr[r], e1 = rowptr[r + 1];
  float dr = dis[r];
  float a0 = 0.f, a1 = 0.f, a2 = 0.f, a3 = 0.f;

  int e = e0;
  for (; e + 1 < e1; e += 2) {
    int cA = cols[e], cB = cols[e + 1];
    float lA = -dr * dis[cA] + (cA == r ? 1.f : 0.f);
    float lB = -dr * dis[cB] + (cB == r ? 1.f : 0.f);
    uint2 uA = *(const uint2*)(v + (size_t)cA * DFEAT + fo);
    uint2 uB = *(const uint2*)(v + (size_t)cB * DFEAT + fo);
    a0 += lA * bf2f(uA.x & 0xffff) + lB * bf2f(uB.x & 0xffff);
    a1 += lA * bf2f(uA.x >> 16)    + lB * bf2f(uB.x >> 16);
    a2 += lA * bf2f(uA.y & 0xffff) + lB * bf2f(uB.y & 0xffff);
    a3 += lA * bf2f(uA.y >> 16)    + lB * bf2f(uB.y >> 16);
  }
  if (e < e1) {
    int c = cols[e];
    float lv = -dr * dis[c] + (c == r ? 1.f : 0.f);
    uint2 u = *(const uint2*)(v + (size_t)c * DFEAT + fo);
    a0 += lv * bf2f(u.x & 0xffff);
    a1 += lv * bf2f(u.x >> 16);
    a2 += lv * bf2f(u.y & 0xffff);
    a3 += lv * bf2f(u.y >> 16);
  }

  float sc = 1.0f - dr * dr;  // appended self-loop
  uint2 uv = *(const uint2*)(v + (size_t)r * DFEAT + fo);
  a0 += sc * bf2f(uv.x & 0xffff);
  a1 += sc * bf2f(uv.x >> 16);
  a2 += sc * bf2f(uv.y & 0xffff);
  a3 += sc * bf2f(uv.y >> 16);

  uint2 o;
  o.x = (unsigned)f2bf(a0) | ((unsigned)f2bf(a1) << 16);
  o.y = (unsigned)f2bf(a2) | ((unsigned)f2bf(a3) << 16);
  *(uint2*)(y + (size_t)r * DFEAT + fo) = o;
}

// ---------------- fused MFMA GEMM: out = sum_g Ag @ Wg' + bias ----------------
// BM=64, BN=256 (full width -> A read exactly once). 4 waves, each 64x64 tile.
// Unified 320-row LDS staging (A rows 0..63, B rows 64..319), 128B/row,
// XOR-swizzled, double-buffered (80 KB -> 2 blocks/CU), 2-phase overlap.

__global__ __launch_bounds__(256) void k_gemm4(
    const unsigned short* __restrict__ A0, const unsigned short* __restrict__ A1,
    const unsigned short* __restrict__ A2, const unsigned short* __restrict__ A3,
    const unsigned short* __restrict__ WT,  // [4][256][256] (g,n,k) combined
    const float* __restrict__ bias, float* __restrict__ C, int N) {
  __shared__ __align__(16) unsigned short lds[2][320 * 64];
  int tid = threadIdx.x;
  int lane = tid & 63;
  int w = tid >> 6;
  int brow = blockIdx.x * 64;

  f32x4 acc[4][4] = {};

  int lrow = lane >> 3;                       // 0..7 within 8-row group
  int sélem = ((lane & 7) ^ lrow) << 3;       // swizzled slot, in elements

  auto stage = [&](int buf, int it) {
    int g = it >> 2;
    int k0 = (it & 3) * 64;
    const unsigned short* Asrc = g == 0 ? A0 : g == 1 ? A1 : g == 2 ? A2 : A3;
    const unsigned short* Bsrc = WT + (g << 16);
#pragma unroll
    for (int c = 0; c < 10; ++c) {
      int gr = c * 32 + w * 8 + lrow;  // 0..319 (8-row groups never straddle 64)
      const unsigned short* src;
      if (gr < 64) {
        int grow = brow + gr;
        if (grow >= N) grow = N - 1;
        src = Asrc + (size_t)grow * DFEAT + k0 + sélem;
      } else {
        src = Bsrc + (size_t)(gr - 64) * DFEAT + k0 + sélem;
      }
      gload_lds16(src, (char*)lds[buf] + (c * 32 + w * 8) * 128);
    }
  };

  stage(0, 0);
  __syncthreads();  // vmcnt(0) + barrier: tile 0 ready

  for (int it = 0; it < 16; ++it) {
    int cur = it & 1;
    if (it < 15) stage(cur ^ 1, it + 1);  // next tile's loads stay in flight
#pragma unroll
    for (int ks = 0; ks < 2; ++ks) {
      bf16x8 af[4], bfr[4];
#pragma unroll
      for (int i = 0; i < 4; ++i) {
        int row = i * 16 + (lane & 15);  // A region rows 0..63
        int kb = (ks * 64 + ((lane >> 4) << 4)) ^ ((row & 7) << 4);
        af[i] = *(const bf16x8*)((const char*)lds[cur] + row * 128 + kb);
      }
#pragma unroll
      for (int j = 0; j < 4; ++j) {
        int n = w * 64 + j * 16 + (lane & 15);  // B region rows 64..319
        int kb = (ks * 64 + ((lane >> 4) << 4)) ^ ((n & 7) << 4);
        bfr[j] = *(const bf16x8*)((const char*)lds[cur] + (64 + n) * 128 + kb);
      }
#pragma unroll
      for (int i = 0; i < 4; ++i)
#pragma unroll
        for (int j = 0; j < 4; ++j)
          acc[i][j] = __builtin_amdgcn_mfma_f32_16x16x32_bf16(af[i], bfr[j], acc[i][j], 0, 0, 0);
    }
    if (it < 15) __syncthreads();  // drain next-tile loads + guard buffer reuse
  }

#pragma unroll
  for (int i = 0; i < 4; ++i) {
    int rowb = brow + i * 16 + (lane >> 4) * 4;
#pragma unroll
    for (int j = 0; j < 4; ++j) {
      int col = w * 64 + j * 16 + (lane & 15);
      float b = bias[col];
#pragma unroll
      for (int q = 0; q < 4; ++q) {
        int r = rowb + q;
        if (r < N) C[(size_t)r * DFEAT + col] = acc[i][j][q] + b;
      }
    }
  }
}

// ---------------- launch ----------------

extern "C" void kernel_launch(void* const* d_in, const int* in_sizes, int n_in,
                              void* d_out, int out_size, void* d_ws, size_t ws_size,
                              hipStream_t stream) {
  const float* x = (const float*)d_in[0];
  const int* ei = (const int*)d_in[1];
  const float* weight = (const float*)d_in[2];
  const float* bias = (const float*)d_in[3];
  float* out = (float*)d_out;

  int N = in_sizes[0] / DFEAT;
  int E = in_sizes[1] / 2;
  const int* ei0 = ei;
  const int* ei1 = ei + E;

  char* ws = (char*)d_ws;
  size_t off = 0;
  auto alloc = [&](size_t bytes) {
    void* p = ws + off;
    off = (off + bytes + 255) & ~(size_t)255;
    return p;
  };
  int* cnt = (int*)alloc((size_t)2 * N * sizeof(int));
  int* cursor = cnt + N;
  int* rowptr = (int*)alloc((size_t)(N + 1) * sizeof(int));
  float* dis = (float*)alloc((size_t)N * sizeof(float));
  int* cols = (int*)alloc((size_t)E * sizeof(int));
  int* incl = (int*)alloc((size_t)N * sizeof(int));
  int* bsum = (int*)alloc(256 * sizeof(int));
  int* boff = (int*)alloc(256 * sizeof(int));
  unsigned short* xbf = (unsigned short*)alloc((size_t)N * DFEAT * 2);
  unsigned short* S1 = (unsigned short*)alloc((size_t)N * DFEAT * 2);
  unsigned short* S2 = (unsigned short*)alloc((size_t)N * DFEAT * 2);
  unsigned short* S3 = (unsigned short*)alloc((size_t)N * DFEAT * 2);
  unsigned short* WT = (unsigned short*)alloc((size_t)4 * DFEAT * DFEAT * 2);

  hipMemsetAsync(cnt, 0, (size_t)2 * N * sizeof(int), stream);

  int eb = (E + 255) / 256;
  int nb = (N + 255) / 256;
  k_count<<<eb, 256, 0, stream>>>(ei0, E, cnt);
  k_scan1<<<nb, 256, 0, stream>>>(cnt, N, incl, bsum, dis);
  k_scan2<<<1, 256, 0, stream>>>(bsum, nb, boff);
  k_scan3<<<nb, 256, 0, stream>>>(cnt, incl, boff, N, E, rowptr);
  k_scatter<<<eb, 256, 0, stream>>>(ei0, ei1, E, rowptr, cursor, cols);

  int n4 = N * DFEAT / 4;
  k_f2bf<<<(n4 + 255) / 256, 256, 0, stream>>>(x, xbf, n4);
  k_wt<<<DFEAT * DFEAT / 256, 256, 0, stream>>>(weight, WT);

  // Pure chain: S1 = L x ; S2 = L S1 ; S3 = L S2
  int sgrid = (N + 3) / 4;
  k_spmm_bf<<<sgrid, 256, 0, stream>>>(xbf, S1, rowptr, cols, dis, N);
  k_spmm_bf<<<sgrid, 256, 0, stream>>>(S1, S2, rowptr, cols, dis, N);
  k_spmm_bf<<<sgrid, 256, 0, stream>>>(S2, S3, rowptr, cols, dis, N);

  int ggrid = (N + 63) / 64;
  k_gemm4<<<ggrid, 256, 0, stream>>>(xbf, S1, S2, S3, WT, bias, out, N);
}

// Round 8
// 332.332 us; speedup vs baseline: 1.1109x; 1.0496x over previous
//
#include <hip/hip_runtime.h>
#include <hip/hip_bf16.h>

#define DFEAT 256

typedef __attribute__((ext_vector_type(8))) short bf16x8;
typedef __attribute__((ext_vector_type(4))) float f32x4;

__device__ __forceinline__ float bf2f(unsigned short u) {
  return __builtin_bit_cast(float, ((unsigned)u) << 16);
}
__device__ __forceinline__ unsigned short f2bf(float f) {
  __hip_bfloat16 h = __float2bfloat16(f);  // RTNE
  return *reinterpret_cast<unsigned short*>(&h);
}
__device__ __forceinline__ void gload_lds16(const void* g, void* l) {
  __builtin_amdgcn_global_load_lds(
      (const __attribute__((address_space(1))) void*)g,
      (__attribute__((address_space(3))) void*)l, 16, 0, 0);
}

// ---------------- CSR construction ----------------

__global__ void k_count(const int* __restrict__ ei0, int E, int* __restrict__ cnt) {
  int i = blockIdx.x * blockDim.x + threadIdx.x;
  if (i < E) atomicAdd(&cnt[ei0[i]], 1);
}

// phase 1: per-block inclusive scan of cnt; block sums; dis = rsqrt(deg+1)
__global__ __launch_bounds__(256) void k_scan1(const int* __restrict__ cnt, int N,
                                               int* __restrict__ incl,
                                               int* __restrict__ bsum,
                                               float* __restrict__ dis) {
  __shared__ int sh[256];
  int t = threadIdx.x;
  int i = blockIdx.x * 256 + t;
  int v = (i < N) ? cnt[i] : 0;
  sh[t] = v;
  __syncthreads();
  for (int o = 1; o < 256; o <<= 1) {
    int u = (t >= o) ? sh[t - o] : 0;
    __syncthreads();
    sh[t] += u;
    __syncthreads();
  }
  if (i < N) {
    incl[i] = sh[t];
    dis[i] = rsqrtf((float)(v + 1));
  }
  if (t == 255) bsum[blockIdx.x] = sh[255];
}

// phase 2 (fused): each block reduces bsum[0..b) itself, then writes rowptr
// and zeroes cursor.
__global__ __launch_bounds__(256) void k_scan3(const int* __restrict__ cnt,
                                               const int* __restrict__ incl,
                                               const int* __restrict__ bsum,
                                               int N, int E,
                                               int* __restrict__ rowptr,
                                               int* __restrict__ cursor) {
  __shared__ int red[64];
  int b = blockIdx.x;
  int t = threadIdx.x;
  int s = 0;
  for (int i = t; i < b; i += 256) s += bsum[i];
#pragma unroll
  for (int o = 32; o; o >>= 1) s += __shfl_down(s, o);
  if ((t & 63) == 0) red[t >> 6] = s;
  __syncthreads();
  int boff = red[0] + red[1] + red[2] + red[3];
  int i = b * 256 + t;
  if (i < N) {
    rowptr[i] = boff + incl[i] - cnt[i];
    cursor[i] = 0;
  }
  if (i == 0) rowptr[N] = E;
}

__global__ void k_scatter(const int* __restrict__ ei0, const int* __restrict__ ei1, int E,
                          const int* __restrict__ rowptr, int* __restrict__ cursor,
                          int* __restrict__ cols) {
  int i = blockIdx.x * blockDim.x + threadIdx.x;
  if (i >= E) return;
  int r = ei0[i];
  int pos = rowptr[r] + atomicAdd(&cursor[r], 1);
  cols[pos] = ei1[i];
}

// ---------------- converts (fused f2bf + weight combine) ----------------
// Blocks [0,256): combined weights for the pure-L chain:
//   out = x(W0-W2) + S1(W1-3W3) + S2(2W2) + S3(4W3) + b,  S_k = L^k x
// Blocks [256,...): x f32 -> bf16, 4 elems/thread.

__global__ __launch_bounds__(256) void k_f2bfwt(const float* __restrict__ x,
                                                unsigned short* __restrict__ xbf, int n4,
                                                const float* __restrict__ W,
                                                unsigned short* __restrict__ WT) {
  int b = blockIdx.x;
  if (b < 256) {
    int idx = b * 256 + threadIdx.x;  // (k,n) over 65536
    int n = idx & 255;
    int k = idx >> 8;
    float w0 = W[idx];
    float w1 = W[65536 + idx];
    float w2 = W[2 * 65536 + idx];
    float w3 = W[3 * 65536 + idx];
    int t = (n << 8) | k;  // transposed (n,k)
    WT[t]             = f2bf(w0 - w2);
    WT[65536 + t]     = f2bf(w1 - 3.0f * w3);
    WT[2 * 65536 + t] = f2bf(2.0f * w2);
    WT[3 * 65536 + t] = f2bf(4.0f * w3);
    return;
  }
  int i = (b - 256) * 256 + threadIdx.x;
  if (i >= n4) return;
  float4 f = *(const float4*)(x + (size_t)i * 4);
  ushort4 u;
  u.x = f2bf(f.x); u.y = f2bf(f.y); u.z = f2bf(f.z); u.w = f2bf(f.w);
  *(ushort4*)(xbf + (size_t)i * 4) = u;
}

// ---------------- SpMM (bf16): y = L v  (pure Laplacian apply) ----------------
// One wave per row; lane owns 4 contiguous feats. Unroll x4: four independent
// gather chains per wave (tests outstanding-miss limit). No LDS/barrier.

__global__ __launch_bounds__(256) void k_spmm_bf(
    const unsigned short* __restrict__ v, unsigned short* __restrict__ y,
    const int* __restrict__ rowptr, const int* __restrict__ cols,
    const float* __restrict__ dis, int N) {
  int r = blockIdx.x * 4 + (threadIdx.x >> 6);
  if (r >= N) return;
  int lane = threadIdx.x & 63;
  int fo = lane * 4;
  int e0 = rowptr[r], e1 = rowptr[r + 1];
  float dr = dis[r];
  float a0 = 0.f, a1 = 0.f, a2 = 0.f, a3 = 0.f;

  int e = e0;
  for (; e + 3 < e1; e += 4) {
    int c0 = cols[e], c1 = cols[e + 1], c2 = cols[e + 2], c3 = cols[e + 3];
    float l0 = -dr * dis[c0] + (c0 == r ? 1.f : 0.f);
    float l1 = -dr * dis[c1] + (c1 == r ? 1.f : 0.f);
    float l2 = -dr * dis[c2] + (c2 == r ? 1.f : 0.f);
    float l3 = -dr * dis[c3] + (c3 == r ? 1.f : 0.f);
    uint2 u0 = *(const uint2*)(v + (size_t)c0 * DFEAT + fo);
    uint2 u1 = *(const uint2*)(v + (size_t)c1 * DFEAT + fo);
    uint2 u2 = *(const uint2*)(v + (size_t)c2 * DFEAT + fo);
    uint2 u3 = *(const uint2*)(v + (size_t)c3 * DFEAT + fo);
    a0 += l0 * bf2f(u0.x & 0xffff) + l1 * bf2f(u1.x & 0xffff) +
          l2 * bf2f(u2.x & 0xffff) + l3 * bf2f(u3.x & 0xffff);
    a1 += l0 * bf2f(u0.x >> 16) + l1 * bf2f(u1.x >> 16) +
          l2 * bf2f(u2.x >> 16) + l3 * bf2f(u3.x >> 16);
    a2 += l0 * bf2f(u0.y & 0xffff) + l1 * bf2f(u1.y & 0xffff) +
          l2 * bf2f(u2.y & 0xffff) + l3 * bf2f(u3.y & 0xffff);
    a3 += l0 * bf2f(u0.y >> 16) + l1 * bf2f(u1.y >> 16) +
          l2 * bf2f(u2.y >> 16) + l3 * bf2f(u3.y >> 16);
  }
  for (; e < e1; ++e) {
    int c = cols[e];
    float lv = -dr * dis[c] + (c == r ? 1.f : 0.f);
    uint2 u = *(const uint2*)(v + (size_t)c * DFEAT + fo);
    a0 += lv * bf2f(u.x & 0xffff);
    a1 += lv * bf2f(u.x >> 16);
    a2 += lv * bf2f(u.y & 0xffff);
    a3 += lv * bf2f(u.y >> 16);
  }

  float sc = 1.0f - dr * dr;  // appended self-loop
  uint2 uv = *(const uint2*)(v + (size_t)r * DFEAT + fo);
  a0 += sc * bf2f(uv.x & 0xffff);
  a1 += sc * bf2f(uv.x >> 16);
  a2 += sc * bf2f(uv.y & 0xffff);
  a3 += sc * bf2f(uv.y >> 16);

  uint2 o;
  o.x = (unsigned)f2bf(a0) | ((unsigned)f2bf(a1) << 16);
  o.y = (unsigned)f2bf(a2) | ((unsigned)f2bf(a3) << 16);
  *(uint2*)(y + (size_t)r * DFEAT + fo) = o;
}

// ---------------- fused MFMA GEMM: out = sum_g Ag @ Wg' + bias ----------------
// BM=64, BN=256 (A read exactly once). 4 waves, 64x64 tile each. Unified
// 320-row LDS (A 0..63, B 64..319), XOR-swizzled, double-buffered, 2-phase
// overlap, setprio around MFMA clusters.

__global__ __launch_bounds__(256) void k_gemm4(
    const unsigned short* __restrict__ A0, const unsigned short* __restrict__ A1,
    const unsigned short* __restrict__ A2, const unsigned short* __restrict__ A3,
    const unsigned short* __restrict__ WT,  // [4][256][256] (g,n,k) combined
    const float* __restrict__ bias, float* __restrict__ C, int N) {
  __shared__ __align__(16) unsigned short lds[2][320 * 64];
  int tid = threadIdx.x;
  int lane = tid & 63;
  int w = tid >> 6;
  int brow = blockIdx.x * 64;

  f32x4 acc[4][4] = {};

  int lrow = lane >> 3;                   // 0..7 within 8-row group
  int selem = ((lane & 7) ^ lrow) << 3;   // swizzled slot, in elements

  auto stage = [&](int buf, int it) {
    int g = it >> 2;
    int k0 = (it & 3) * 64;
    const unsigned short* Asrc = g == 0 ? A0 : g == 1 ? A1 : g == 2 ? A2 : A3;
    const unsigned short* Bsrc = WT + (g << 16);
#pragma unroll
    for (int c = 0; c < 10; ++c) {
      int gr = c * 32 + w * 8 + lrow;  // 0..319
      const unsigned short* src;
      if (gr < 64) {
        int grow = brow + gr;
        if (grow >= N) grow = N - 1;
        src = Asrc + (size_t)grow * DFEAT + k0 + selem;
      } else {
        src = Bsrc + (size_t)(gr - 64) * DFEAT + k0 + selem;
      }
      gload_lds16(src, (char*)lds[buf] + (c * 32 + w * 8) * 128);
    }
  };

  stage(0, 0);
  __syncthreads();  // vmcnt(0) + barrier: tile 0 ready

  for (int it = 0; it < 16; ++it) {
    int cur = it & 1;
    if (it < 15) stage(cur ^ 1, it + 1);  // next tile's loads stay in flight
#pragma unroll
    for (int ks = 0; ks < 2; ++ks) {
      bf16x8 af[4], bfr[4];
#pragma unroll
      for (int i = 0; i < 4; ++i) {
        int row = i * 16 + (lane & 15);  // A region rows 0..63
        int kb = (ks * 64 + ((lane >> 4) << 4)) ^ ((row & 7) << 4);
        af[i] = *(const bf16x8*)((const char*)lds[cur] + row * 128 + kb);
      }
#pragma unroll
      for (int j = 0; j < 4; ++j) {
        int n = w * 64 + j * 16 + (lane & 15);  // B region rows 64..319
        int kb = (ks * 64 + ((lane >> 4) << 4)) ^ ((n & 7) << 4);
        bfr[j] = *(const bf16x8*)((const char*)lds[cur] + (64 + n) * 128 + kb);
      }
      __builtin_amdgcn_s_setprio(1);
#pragma unroll
      for (int i = 0; i < 4; ++i)
#pragma unroll
        for (int j = 0; j < 4; ++j)
          acc[i][j] = __builtin_amdgcn_mfma_f32_16x16x32_bf16(af[i], bfr[j], acc[i][j], 0, 0, 0);
      __builtin_amdgcn_s_setprio(0);
    }
    if (it < 15) __syncthreads();  // drain next-tile loads + guard buffer reuse
  }

#pragma unroll
  for (int i = 0; i < 4; ++i) {
    int rowb = brow + i * 16 + (lane >> 4) * 4;
#pragma unroll
    for (int j = 0; j < 4; ++j) {
      int col = w * 64 + j * 16 + (lane & 15);
      float b = bias[col];
#pragma unroll
      for (int q = 0; q < 4; ++q) {
        int r = rowb + q;
        if (r < N) C[(size_t)r * DFEAT + col] = acc[i][j][q] + b;
      }
    }
  }
}

// ---------------- launch ----------------

extern "C" void kernel_launch(void* const* d_in, const int* in_sizes, int n_in,
                              void* d_out, int out_size, void* d_ws, size_t ws_size,
                              hipStream_t stream) {
  const float* x = (const float*)d_in[0];
  const int* ei = (const int*)d_in[1];
  const float* weight = (const float*)d_in[2];
  const float* bias = (const float*)d_in[3];
  float* out = (float*)d_out;

  int N = in_sizes[0] / DFEAT;
  int E = in_sizes[1] / 2;
  const int* ei0 = ei;
  const int* ei1 = ei + E;

  char* ws = (char*)d_ws;
  size_t off = 0;
  auto alloc = [&](size_t bytes) {
    void* p = ws + off;
    off = (off + bytes + 255) & ~(size_t)255;
    return p;
  };
  int* cnt = (int*)alloc((size_t)N * sizeof(int));
  int* cursor = (int*)alloc((size_t)N * sizeof(int));
  int* rowptr = (int*)alloc((size_t)(N + 1) * sizeof(int));
  float* dis = (float*)alloc((size_t)N * sizeof(float));
  int* cols = (int*)alloc((size_t)E * sizeof(int));
  int* incl = (int*)alloc((size_t)N * sizeof(int));
  int* bsum = (int*)alloc(256 * sizeof(int));
  unsigned short* xbf = (unsigned short*)alloc((size_t)N * DFEAT * 2);
  unsigned short* S1 = (unsigned short*)alloc((size_t)N * DFEAT * 2);
  unsigned short* S2 = (unsigned short*)alloc((size_t)N * DFEAT * 2);
  unsigned short* S3 = (unsigned short*)alloc((size_t)N * DFEAT * 2);
  unsigned short* WT = (unsigned short*)alloc((size_t)4 * DFEAT * DFEAT * 2);

  hipMemsetAsync(cnt, 0, (size_t)N * sizeof(int), stream);

  int eb = (E + 255) / 256;
  int nb = (N + 255) / 256;
  k_count<<<eb, 256, 0, stream>>>(ei0, E, cnt);
  k_scan1<<<nb, 256, 0, stream>>>(cnt, N, incl, bsum, dis);
  k_scan3<<<nb, 256, 0, stream>>>(cnt, incl, bsum, N, E, rowptr, cursor);
  k_scatter<<<eb, 256, 0, stream>>>(ei0, ei1, E, rowptr, cursor, cols);

  int n4 = N * DFEAT / 4;
  k_f2bfwt<<<256 + (n4 + 255) / 256, 256, 0, stream>>>(x, xbf, n4, weight, WT);

  // Pure chain: S1 = L x ; S2 = L S1 ; S3 = L S2
  int sgrid = (N + 3) / 4;
  k_spmm_bf<<<sgrid, 256, 0, stream>>>(xbf, S1, rowptr, cols, dis, N);
  k_spmm_bf<<<sgrid, 256, 0, stream>>>(S1, S2, rowptr, cols, dis, N);
  k_spmm_bf<<<sgrid, 256, 0, stream>>>(S2, S3, rowptr, cols, dis, N);

  int ggrid = (N + 63) / 64;
  k_gemm4<<<ggrid, 256, 0, stream>>>(xbf, S1, S2, S3, WT, bias, out, N);
}